// Round 6
// baseline (214.325 us; speedup 1.0000x reference)
//
#include <hip/hip_runtime.h>
#include <hip/hip_bf16.h>
#include <math.h>

// Problem constants
#define BATCH 8
#define SEQ   2048
#define CH    512
#define ROWS  (BATCH * SEQ)   // 16384
#define INVSQ 0.044194173824159216f  // 1/sqrt(512)

#define TP 68                  // transpose-tile pitch (2-way conflict = free)

typedef __attribute__((ext_vector_type(8))) __bf16 bf16x8;
typedef __attribute__((ext_vector_type(4))) float f32x4;

__device__ inline unsigned short f2bf(float f) {
    unsigned u = __builtin_bit_cast(unsigned, f);
    u += 0x7fffu + ((u >> 16) & 1u);   // round-to-nearest-even
    return (unsigned short)(u >> 16);
}
__device__ inline float bf2f(unsigned short s) {
    unsigned u = ((unsigned)s) << 16;
    return __builtin_bit_cast(float, u);
}

// ---------------------------------------------------------------------------
// fuse_x: x fp32 [16384,512] -> out[:, :, 0:512] (fp32) AND xb (bf16).
// Also zeroes Z (blocks 0..63).
// ---------------------------------------------------------------------------
__global__ __launch_bounds__(256) void fuse_x_kernel(
    const float* __restrict__ x, unsigned short* __restrict__ xb,
    float* __restrict__ out, float* __restrict__ Z)
{
    if (blockIdx.x < 64) Z[blockIdx.x * 256 + threadIdx.x] = 0.f;
    size_t base = ((size_t)blockIdx.x * 256 + threadIdx.x) * 8;
    size_t row = base >> 9, c = base & 511;
    float4 v0 = *(const float4*)(x + base);
    float4 v1 = *(const float4*)(x + base + 4);
    float* o = out + row * 1024 + c;
    *(float4*)o = v0;
    *(float4*)(o + 4) = v1;
    alignas(16) unsigned short t[8];
    t[0] = f2bf(v0.x); t[1] = f2bf(v0.y); t[2] = f2bf(v0.z); t[3] = f2bf(v0.w);
    t[4] = f2bf(v1.x); t[5] = f2bf(v1.y); t[6] = f2bf(v1.z); t[7] = f2bf(v1.w);
    *(uint4*)(xb + base) = *(const uint4*)t;
}

// ---------------------------------------------------------------------------
// transpose_w: W fp32 [512 k][512 n] -> Wt bf16 [3][512 n][512 k]
// ---------------------------------------------------------------------------
__global__ __launch_bounds__(256) void transpose_w_kernel(
    const float* __restrict__ Wq, const float* __restrict__ Wk,
    const float* __restrict__ Wv, unsigned short* __restrict__ Wt)
{
    __shared__ unsigned short T[64 * TP];
    const int k0 = blockIdx.x * 64, n0 = blockIdx.y * 64, w = blockIdx.z;
    const float* W = (w == 0) ? Wq : (w == 1) ? Wk : Wv;
    const int tid = threadIdx.x;
#pragma unroll
    for (int i = 0; i < 2; ++i) {
        int slot = tid + i * 256;
        int kr = slot >> 3, c8 = (slot & 7) << 3;
        float4 a = *(const float4*)(W + (size_t)(k0 + kr) * CH + n0 + c8);
        float4 b = *(const float4*)(W + (size_t)(k0 + kr) * CH + n0 + c8 + 4);
        T[(c8 + 0) * TP + kr] = f2bf(a.x); T[(c8 + 1) * TP + kr] = f2bf(a.y);
        T[(c8 + 2) * TP + kr] = f2bf(a.z); T[(c8 + 3) * TP + kr] = f2bf(a.w);
        T[(c8 + 4) * TP + kr] = f2bf(b.x); T[(c8 + 5) * TP + kr] = f2bf(b.y);
        T[(c8 + 6) * TP + kr] = f2bf(b.z); T[(c8 + 7) * TP + kr] = f2bf(b.w);
    }
    __syncthreads();
#pragma unroll
    for (int i = 0; i < 2; ++i) {
        int slot = tid + i * 256;
        int nr = slot >> 3, k8 = (slot & 7) << 3;
        uint2 lo = *(const uint2*)(T + nr * TP + k8);
        uint2 hi = *(const uint2*)(T + nr * TP + k8 + 4);
        uint4 u; u.x = lo.x; u.y = lo.y; u.z = hi.x; u.w = hi.y;
        *(uint4*)(Wt + ((size_t)w * CH + n0 + nr) * CH + k0 + k8) = u;
    }
}

// ---------------------------------------------------------------------------
// transpose_v: vb bf16 [b][s][v] -> Vt bf16 [b][v][s], scaled by 1/Z[b][s].
// ---------------------------------------------------------------------------
__global__ __launch_bounds__(256) void transpose_v_kernel(
    const unsigned short* __restrict__ vb, const float* __restrict__ Z,
    unsigned short* __restrict__ Vt)
{
    __shared__ unsigned short T[64 * TP];
    const int s0 = blockIdx.x * 64, v0 = blockIdx.y * 64, b = blockIdx.z;
    const int tid = threadIdx.x;
#pragma unroll
    for (int i = 0; i < 2; ++i) {
        int slot = tid + i * 256;
        int sr = slot >> 3, c8 = (slot & 7) << 3;
        float inv = 1.0f / Z[b * SEQ + s0 + sr];
        uint4 raw = *(const uint4*)(vb + ((size_t)b * SEQ + s0 + sr) * CH + v0 + c8);
        const unsigned short* p = (const unsigned short*)&raw;
#pragma unroll
        for (int j = 0; j < 8; ++j)
            T[(c8 + j) * TP + sr] = f2bf(bf2f(p[j]) * inv);
    }
    __syncthreads();
#pragma unroll
    for (int i = 0; i < 2; ++i) {
        int slot = tid + i * 256;
        int vr = slot >> 3, s8 = (slot & 7) << 3;
        uint2 lo = *(const uint2*)(T + vr * TP + s8);
        uint2 hi = *(const uint2*)(T + vr * TP + s8 + 4);
        uint4 u; u.x = lo.x; u.y = lo.y; u.z = hi.x; u.w = hi.y;
        *(uint4*)(Vt + ((size_t)b * CH + v0 + vr) * SEQ + s0 + s8) = u;
    }
}

// ---------------------------------------------------------------------------
// 128x128-tile BK=64 single-barrier deep pipeline, 256 thr / 4 waves.
// LDS 80 KB: A[2][128][64] | B[3][128][64] bf16 (B triple-buffered).
// Swizzle as before (involution chunk^=(row&7) on 16-B slots, both sides).
// Per tile U:
//   stageA(U+1) [-> A[(U+1)&1]; WAR vs A(U-1) reads: done before prev bar]
//   stageB(U+2) [-> B[(U+2)%3]; WAR vs B(U-1) reads: done before prev bar]
//   issue 8 h0 ds_reads | 8 h1 ds_reads (order pinned by sched_barrier)
//   lgkmcnt(8)  -> h0 landed, h1 in flight
//   MFMA h0 (16)            [ds ∥ MFMA overlap]
//   lgkmcnt(0) -> all reads done (prereq for next tile's DMA overwrite)
//   MFMA h1 (16)
//   vmcnt(4) [A(U+1),B(U+1) retired; only B(U+2) in flight]   (tail: 0)
//   s_barrier [publishes DMA cross-wave; gates next tile's stages]
// RAW at tile start: prev tile's vmcnt+barrier guarantees A(U),B(U) visible.
// ---------------------------------------------------------------------------
#define STAGE4(gsrc, dslab)                                                   \
    _Pragma("unroll")                                                         \
    for (int p = 0; p < 4; ++p)                                               \
        __builtin_amdgcn_global_load_lds(                                     \
            (const __attribute__((address_space(1))) unsigned int*)((gsrc) + (size_t)p * 32 * gstride), \
            (__attribute__((address_space(3))) unsigned int*)((dslab) + p * 2048 + (tid << 3)), \
            16, 0, 0);

#define PIPE_PROLOGUE                                                         \
    stageA(0); stageB(0); stageB(1);                                          \
    asm volatile("s_waitcnt vmcnt(4)" ::: "memory");                          \
    __builtin_amdgcn_s_barrier();                                             \
    __builtin_amdgcn_sched_barrier(0);

#define PIPE_BODY(NTv)                                                        \
    {                                                                         \
        const unsigned short* Ab = lds + (U & 1) * 8192;                      \
        const unsigned short* Bb = lds + 16384 + (U % 3) * 8192;              \
        stageA(U + 1);                                                        \
        stageB(U + 2);                                                        \
        bf16x8 a0[4], a1[4], c0[4], c1[4];                                    \
        _Pragma("unroll")                                                     \
        for (int rr = 0; rr < 4; ++rr) {                                      \
            a0[rr] = *(const bf16x8*)(Ab + (arow + rr * 16) * 64 + s80);      \
            c0[rr] = *(const bf16x8*)(Bb + (brow + rr * 16) * 64 + s80);      \
        }                                                                     \
        __builtin_amdgcn_sched_barrier(0);                                    \
        _Pragma("unroll")                                                     \
        for (int rr = 0; rr < 4; ++rr) {                                      \
            a1[rr] = *(const bf16x8*)(Ab + (arow + rr * 16) * 64 + s81);      \
            c1[rr] = *(const bf16x8*)(Bb + (brow + rr * 16) * 64 + s81);      \
        }                                                                     \
        asm volatile("s_waitcnt lgkmcnt(8)" ::: "memory");                    \
        __builtin_amdgcn_sched_barrier(0);                                    \
        __builtin_amdgcn_s_setprio(1);                                        \
        _Pragma("unroll")                                                     \
        for (int rr = 0; rr < 4; ++rr)                                        \
            _Pragma("unroll")                                                 \
            for (int cc = 0; cc < 4; ++cc)                                    \
                acc[rr][cc] = __builtin_amdgcn_mfma_f32_16x16x32_bf16(        \
                    a0[rr], c0[cc], acc[rr][cc], 0, 0, 0);                    \
        __builtin_amdgcn_s_setprio(0);                                        \
        asm volatile("s_waitcnt lgkmcnt(0)" ::: "memory");                    \
        __builtin_amdgcn_sched_barrier(0);                                    \
        __builtin_amdgcn_s_setprio(1);                                        \
        _Pragma("unroll")                                                     \
        for (int rr = 0; rr < 4; ++rr)                                        \
            _Pragma("unroll")                                                 \
            for (int cc = 0; cc < 4; ++cc)                                    \
                acc[rr][cc] = __builtin_amdgcn_mfma_f32_16x16x32_bf16(        \
                    a1[rr], c1[cc], acc[rr][cc], 0, 0, 0);                    \
        __builtin_amdgcn_s_setprio(0);                                        \
        if (U <= (NTv) - 3)      asm volatile("s_waitcnt vmcnt(4)" ::: "memory"); \
        else if (U == (NTv) - 2) asm volatile("s_waitcnt vmcnt(0)" ::: "memory"); \
        __builtin_amdgcn_s_barrier();                                         \
        __builtin_amdgcn_sched_barrier(0);                                    \
    }

// ---------------------------------------------------------------------------
// qkv fused GEMM. C[wr(weight row), m(x row)]: A = Wt [1536][512] k-major,
// B = xb [16384][512]. Tile 128(w) x 128(x), BK=64, 8 K-tiles.
// Grid 1536 = 128 xt x 12 wt; bijective XCD swizzle (1536 = 8 x 192).
// ---------------------------------------------------------------------------
__global__ __launch_bounds__(256, 2) void qkv8_kernel(
    const unsigned short* __restrict__ xb, const unsigned short* __restrict__ Wt,
    const float* __restrict__ bq, const float* __restrict__ bk,
    const float* __restrict__ bv, unsigned short* __restrict__ qkv)
{
    __shared__ unsigned short lds[40960];   // 80 KB: A 2x16K | B 3x16K
    const int tid = threadIdx.x;
    const int lane = tid & 63, wave = tid >> 6;
    const int waveA = wave >> 1;            // 0..1: weight strip (64 rows)
    const int waveB = wave & 1;             // 0..1: x strip (64 rows)
    const int quad = lane >> 4, l16 = lane & 15;

    int id = (int)blockIdx.x;
    id = (id & 7) * 192 + (id >> 3);        // XCD c owns x-tiles 16c..16c+15
    const int xt = id / 12, wt = id - xt * 12;
    const int xrow0 = xt << 7, wrow0 = wt << 7;

    const size_t gstride = CH;
    const unsigned short* __restrict__ Wg = Wt + (size_t)wrow0 * CH;
    const unsigned short* __restrict__ Xg = xb + (size_t)xrow0 * CH;

    // Staging: rows tid>>3 (+32 per pass), source chunk pre-swizzled.
    const int scol = (((tid & 7) ^ ((tid >> 3) & 7)) << 3);
    const size_t ga = (size_t)(tid >> 3) * gstride + scol;
    // Read-side swizzle: slot (h*4+quad)^(row&7), row&7 == l16&7.
    const int s80 = ((quad ^ (l16 & 7)) << 3);
    const int s81 = s80 ^ 32;
    const int arow = waveA * 64 + l16;
    const int brow = waveB * 64 + l16;

    f32x4 acc[4][4] = {};

    auto stageA = [&](int V) {
        if (V >= 8) return;
        const unsigned short* g = Wg + ga + V * 64;
        unsigned short* d = lds + (V & 1) * 8192;
        STAGE4(g, d)
    };
    auto stageB = [&](int V) {
        if (V >= 8) return;
        const unsigned short* g = Xg + ga + V * 64;
        unsigned short* d = lds + 16384 + (V % 3) * 8192;
        STAGE4(g, d)
    };

    PIPE_PROLOGUE
#pragma unroll
    for (int U = 0; U < 8; ++U) PIPE_BODY(8)

    const int which = wrow0 >> 9;   // uniform per block
    const float* bias = (which == 0) ? bq : (which == 1) ? bk : bv;
    const float scale = (which == 0) ? INVSQ : 1.0f;
    unsigned short* outw = qkv + (size_t)which * ROWS * CH;
    const int colblk = wrow0 & 511;
#pragma unroll
    for (int r = 0; r < 4; ++r) {
        int colb = colblk + waveA * 64 + r * 16 + quad * 4;
        float4 b4 = *(const float4*)(bias + colb);
#pragma unroll
        for (int c = 0; c < 4; ++c) {
            int m = xrow0 + waveB * 64 + c * 16 + l16;
            alignas(8) unsigned short pk[4];
            pk[0] = f2bf((acc[r][c][0] + b4.x) * scale);
            pk[1] = f2bf((acc[r][c][1] + b4.y) * scale);
            pk[2] = f2bf((acc[r][c][2] + b4.z) * scale);
            pk[3] = f2bf((acc[r][c][3] + b4.w) * scale);
            *(uint2*)(outw + (size_t)m * CH + colb) = *(const uint2*)pk;
        }
    }
}

// ---------------------------------------------------------------------------
// logits: C[s][t] = k_s . q_t (q pre-scaled). A = K-tile [128 s][512 k],
// B = Q-tile [128 t][512 k]. Triangle st<=tt: 136 pairs x 8 b = 1088 blocks.
// b = blockIdx&7 pins batch to XCD. E[t][s] = exp(C) if s<=t else 0;
// Z[s] via shuffle+atomic.
// ---------------------------------------------------------------------------
__global__ __launch_bounds__(256, 2) void logits8_kernel(
    const unsigned short* __restrict__ qb, const unsigned short* __restrict__ kb,
    unsigned short* __restrict__ E, float* __restrict__ Z)
{
    __shared__ unsigned short lds[40960];   // 80 KB
    const int tid = threadIdx.x;
    const int lane = tid & 63, wave = tid >> 6;
    const int waveA = wave >> 1;            // 0..1: s strip
    const int waveB = wave & 1;             // 0..1: t strip
    const int quad = lane >> 4, l16 = lane & 15;

    const int b = (int)blockIdx.x & 7;
    const int i = (int)blockIdx.x >> 3;     // 0..135 triangle index
    int tt = (int)((sqrtf(8.f * (float)i + 1.f) - 1.f) * 0.5f);
    int st = i - ((tt * (tt + 1)) >> 1);
    while (st < 0)  { --tt; st = i - ((tt * (tt + 1)) >> 1); }
    while (st > tt) { ++tt; st = i - ((tt * (tt + 1)) >> 1); }
    const int m0s = st << 7;    // s rows (A, from k)
    const int n0t = tt << 7;    // t rows (B, from q)

    const size_t gstride = CH;
    const unsigned short* __restrict__ Ag = kb + ((size_t)b * SEQ + m0s) * CH;
    const unsigned short* __restrict__ Bg = qb + ((size_t)b * SEQ + n0t) * CH;

    const int scol = (((tid & 7) ^ ((tid >> 3) & 7)) << 3);
    const size_t ga = (size_t)(tid >> 3) * gstride + scol;
    const int s80 = ((quad ^ (l16 & 7)) << 3);
    const int s81 = s80 ^ 32;
    const int arow = waveA * 64 + l16;
    const int brow = waveB * 64 + l16;

    f32x4 acc[4][4] = {};

    auto stageA = [&](int V) {
        if (V >= 8) return;
        const unsigned short* g = Ag + ga + V * 64;
        unsigned short* d = lds + (V & 1) * 8192;
        STAGE4(g, d)
    };
    auto stageB = [&](int V) {
        if (V >= 8) return;
        const unsigned short* g = Bg + ga + V * 64;
        unsigned short* d = lds + 16384 + (V % 3) * 8192;
        STAGE4(g, d)
    };

    PIPE_PROLOGUE
#pragma unroll
    for (int U = 0; U < 8; ++U) PIPE_BODY(8)

    // Epilogue: causal mask, exp, Z partial sums, bf16 E write.
#pragma unroll
    for (int r = 0; r < 4; ++r) {
        int sb = m0s + waveA * 64 + r * 16 + quad * 4;
        float ev[4][4];
#pragma unroll
        for (int c = 0; c < 4; ++c) {
            int t = n0t + waveB * 64 + c * 16 + l16;
#pragma unroll
            for (int reg = 0; reg < 4; ++reg)
                ev[c][reg] = (sb + reg <= t) ? __expf(acc[r][c][reg]) : 0.f;
        }
#pragma unroll
        for (int reg = 0; reg < 4; ++reg) {
            float z = ev[0][reg] + ev[1][reg] + ev[2][reg] + ev[3][reg];
            z += __shfl_xor(z, 1);
            z += __shfl_xor(z, 2);
            z += __shfl_xor(z, 4);
            z += __shfl_xor(z, 8);
            if (l16 == 0) atomicAdd(&Z[b * SEQ + sb + reg], z);
        }
#pragma unroll
        for (int c = 0; c < 4; ++c) {
            int t = n0t + waveB * 64 + c * 16 + l16;
            alignas(8) unsigned short pk[4];
            pk[0] = f2bf(ev[c][0]); pk[1] = f2bf(ev[c][1]);
            pk[2] = f2bf(ev[c][2]); pk[3] = f2bf(ev[c][3]);
            *(uint2*)(E + ((size_t)b * SEQ + t) * SEQ + sb) = *(const uint2*)pk;
        }
    }
}

// ---------------------------------------------------------------------------
// read: C[v][t] = sum_s Vt[v][s] * E[t][s]. A = Vt tile [128 v][s],
// B = E tile [128 t][s], both stride SEQ. BK=64, runtime NT = 2*(tt+1).
// Grid 512 (4v x 16tt-balanced x 8b), b = blockIdx&7 pins XCD.
// ---------------------------------------------------------------------------
__global__ __launch_bounds__(256, 2) void read8_kernel(
    const unsigned short* __restrict__ E, const unsigned short* __restrict__ Vt,
    float* __restrict__ out)
{
    __shared__ unsigned short lds[40960];   // 80 KB
    const int tid = threadIdx.x;
    const int lane = tid & 63, wave = tid >> 6;
    const int waveA = wave >> 1;            // 0..1: v strip
    const int waveB = wave & 1;             // 0..1: t strip
    const int quad = lane >> 4, l16 = lane & 15;

    const int id = blockIdx.x;
    const int b = id & 7;
    const int rem = id >> 3;
    const int mv = rem & 3;                  // v tile (4)
    const int r0 = rem >> 2;                 // 0..15
    const int tt = (r0 < 8) ? r0 : 23 - r0;  // paired so per-CU work balances
    const int m0v = mv << 7;
    const int n0t = tt << 7;
    const int NT = (tt + 1) * 2;             // K-tiles of 64 (causal extent)

    const size_t gstride = SEQ;
    const unsigned short* __restrict__ Ag = Vt + ((size_t)b * CH + m0v) * SEQ;
    const unsigned short* __restrict__ Bg = E + ((size_t)b * SEQ + n0t) * SEQ;

    const int scol = (((tid & 7) ^ ((tid >> 3) & 7)) << 3);
    const size_t ga = (size_t)(tid >> 3) * gstride + scol;
    const int s80 = ((quad ^ (l16 & 7)) << 3);
    const int s81 = s80 ^ 32;
    const int arow = waveA * 64 + l16;
    const int brow = waveB * 64 + l16;

    f32x4 acc[4][4] = {};

    auto stageA = [&](int V) {
        if (V >= NT) return;
        const unsigned short* g = Ag + ga + V * 64;
        unsigned short* d = lds + (V & 1) * 8192;
        STAGE4(g, d)
    };
    auto stageB = [&](int V) {
        if (V >= NT) return;
        const unsigned short* g = Bg + ga + V * 64;
        unsigned short* d = lds + 16384 + (V % 3) * 8192;
        STAGE4(g, d)
    };

    PIPE_PROLOGUE
#pragma unroll 2
    for (int U = 0; U < NT; ++U) PIPE_BODY(NT)

#pragma unroll
    for (int r = 0; r < 4; ++r) {
        int v = 512 + m0v + waveA * 64 + r * 16 + quad * 4;
#pragma unroll
        for (int c = 0; c < 4; ++c) {
            int t = n0t + waveB * 64 + c * 16 + l16;
            float4 f;
            f.x = acc[r][c][0]; f.y = acc[r][c][1];
            f.z = acc[r][c][2]; f.w = acc[r][c][3];
            *(float4*)(out + ((size_t)b * SEQ + t) * 1024 + v) = f;
        }
    }
}

extern "C" void kernel_launch(void* const* d_in, const int* in_sizes, int n_in,
                              void* d_out, int out_size, void* d_ws, size_t ws_size,
                              hipStream_t stream) {
    const float* x  = (const float*)d_in[0];
    const float* Wq = (const float*)d_in[1];
    const float* bq = (const float*)d_in[2];
    const float* Wk = (const float*)d_in[3];
    const float* bk = (const float*)d_in[4];
    const float* Wv = (const float*)d_in[5];
    const float* bv = (const float*)d_in[6];
    float* out = (float*)d_out;

    char* ws = (char*)d_ws;
    const size_t QKV_BYTES = (size_t)ROWS * CH * 2;              // 16,777,216
    const size_t E_BYTES   = (size_t)BATCH * SEQ * SEQ * 2;      // 67,108,864
    unsigned short* qkv = (unsigned short*)ws;                   // q,k,v contiguous
    unsigned short* qb = qkv;
    unsigned short* kb = (unsigned short*)(ws + QKV_BYTES);
    unsigned short* vb = (unsigned short*)(ws + 2 * QKV_BYTES);
    unsigned short* E  = (unsigned short*)(ws + 3 * QKV_BYTES);
    float* Z = (float*)(ws + 3 * QKV_BYTES + E_BYTES);
    // Aliases (lifetimes disjoint on the in-order stream):
    unsigned short* xb = E;                                       // dead before logits writes E
    unsigned short* Wt = (unsigned short*)((char*)E + QKV_BYTES); // dead before logits writes E
    unsigned short* Vt = qb;                                      // qb dead after logits

    dim3 blk(256);
    fuse_x_kernel<<<dim3(4096), blk, 0, stream>>>(x, xb, out, Z);
    transpose_w_kernel<<<dim3(8, 8, 3), blk, 0, stream>>>(Wq, Wk, Wv, Wt);
    qkv8_kernel<<<dim3(1536), blk, 0, stream>>>(xb, Wt, bq, bk, bv, qkv);
    logits8_kernel<<<dim3(1088), blk, 0, stream>>>(qb, kb, E, Z);
    transpose_v_kernel<<<dim3(32, 8, 8), blk, 0, stream>>>(vb, Z, Vt);
    read8_kernel<<<dim3(512), blk, 0, stream>>>(E, Vt, out);
}